// Round 1
// baseline (337.495 us; speedup 1.0000x reference)
//
#include <hip/hip_runtime.h>

typedef _Float16 f16;
typedef _Float16 f16x8 __attribute__((ext_vector_type(8)));
typedef float f32x4 __attribute__((ext_vector_type(4)));

#define MFMA16(A, B, C) __builtin_amdgcn_mfma_f32_16x16x32_f16((A), (B), (C), 0, 0, 0)

// B=4, N=512, X_DIM=64, T_DIM=32, H=128
// Block: 256 threads (4 waves), tile 32 i x 32 j. Grid (16,16,4).
// Each wave: 8 i-rows; per chunk: 1 i-row x 32 j = 32 pairs through full MLP.
// All layers computed transposed so MFMA C/D output feeds next layer's B operand in-register.

__global__ __launch_bounds__(256, 2)
void pairmlp_kernel(const float* __restrict__ x, const float* __restrict__ y,
                    const float* __restrict__ t, const float* __restrict__ W1,
                    const float* __restrict__ b1, const float* __restrict__ W2,
                    const float* __restrict__ b2, const float* __restrict__ W3,
                    const float* __restrict__ b3, float* __restrict__ out)
{
    const int N = 512, H = 128, XD = 64, TD = 32;

    __shared__ f16x8 W1a[1024];   // 16 KB: [ht*2+ks][g][c] oct: W1[32ks+8g+i][16ht+c]
    __shared__ f16x8 W2a[2048];   // 32 KB: [hpt*4+ks][g][c] oct: W2[32ks+16(i>=4)+4g+(i&3)][16hpt+c]
    __shared__ f16x8 W3a[256];    //  4 KB: [ks][g][c] oct: c==0 ? W3[h(ks,g,i)] : 0
    __shared__ f16x8 xt[256];     //  4 KB: x tile [32][64] f16, octet idx = row*8 + d/8
    __shared__ f16x8 yt[256];     //  4 KB: y tile, octet idx = row*8 + (q ^ (row&7))  (bank swizzle)
    __shared__ float tbs[128];    // t @ W1[64:] + b1, per block batch

    const int tid = threadIdx.x;
    const int b = blockIdx.z;
    const int ibase = blockIdx.y * 32;
    const int jbase = blockIdx.x * 32;

    // ---------------- staging ----------------
    for (int o = tid; o < 1024; o += 256) {
        int c = o & 15, g = (o >> 4) & 3, kh = o >> 6;   // kh = ht*2+ks
        int ks = kh & 1, ht = kh >> 1;
        int h = ht * 16 + c;
        f16x8 v;
#pragma unroll
        for (int i = 0; i < 8; ++i) {
            int d = 32 * ks + 8 * g + i;
            v[i] = (f16)W1[d * H + h];
        }
        W1a[o] = v;
    }
    for (int o = tid; o < 2048; o += 256) {
        int c = o & 15, g = (o >> 4) & 3, kh = o >> 6;   // kh = hpt*4+ks
        int ks = kh & 3, hpt = kh >> 2;
        int hp = hpt * 16 + c;
        f16x8 v;
#pragma unroll
        for (int i = 0; i < 8; ++i) {
            int h = 32 * ks + ((i >> 2) << 4) + 4 * g + (i & 3);
            v[i] = (f16)W2[h * H + hp];
        }
        W2a[o] = v;
    }
    {
        int o = tid;                                      // 256 octets
        int c = o & 15, g = (o >> 4) & 3, ks = o >> 6;
        f16x8 v;
#pragma unroll
        for (int i = 0; i < 8; ++i) {
            int h = 32 * ks + ((i >> 2) << 4) + 4 * g + (i & 3);
            v[i] = (c == 0) ? (f16)W3[h] : (f16)0.f;
        }
        W3a[o] = v;
    }
    if (tid < 128) {
        float s = b1[tid];
#pragma unroll 8
        for (int d = 0; d < TD; ++d)
            s += t[b * TD + d] * W1[(XD + d) * H + tid];
        tbs[tid] = s;
    }
    {
        int o = tid;                  // 256 octets per tile
        int r = o >> 3, q = o & 7;
        const float* xp = x + ((size_t)(b * N + ibase + r)) * XD + q * 8;
        f16x8 v;
#pragma unroll
        for (int e = 0; e < 8; ++e) v[e] = (f16)xp[e];
        xt[o] = v;
        const float* yp = y + ((size_t)(b * N + jbase + r)) * XD + q * 8;
        f16x8 u;
#pragma unroll
        for (int e = 0; e < 8; ++e) u[e] = (f16)yp[e];
        yt[r * 8 + (q ^ (r & 7))] = u;
    }
    __syncthreads();

    const int w = tid >> 6;
    const int l = tid & 63;
    const int c = l & 15;
    const int g = l >> 4;

    // per-lane bias octets (index map h = 32ks + 16*(i>=4) + 4g + (i&3))
    f16x8 tbo[4], b2o[4];
#pragma unroll
    for (int ks = 0; ks < 4; ++ks) {
        f16x8 v, u;
#pragma unroll
        for (int i = 0; i < 8; ++i) {
            int h = 32 * ks + ((i >> 2) << 4) + 4 * g + (i & 3);
            v[i] = (f16)tbs[h];
            u[i] = (f16)b2[h];
        }
        tbo[ks] = v; b2o[ks] = u;
    }
    const float b3v = b3[0];

    for (int ci = 0; ci < 8; ++ci) {
        const int il = w * 8 + ci;

        // x octets for this i-row: d = 32ks + 8g + e
        float xf[2][8];
        {
            f16x8 x0 = xt[il * 8 + g];
            f16x8 x1 = xt[il * 8 + 4 + g];
#pragma unroll
            for (int i = 0; i < 8; ++i) { xf[0][i] = (float)x0[i]; xf[1][i] = (float)x1[i]; }
        }

        // ---- layer 1: h1^T = W1^T * diff^T  (acc1[ht][mt][r] = h1T[16ht+4g+r][16mt+c]) ----
        f32x4 acc1[8][2];
#pragma unroll
        for (int a = 0; a < 8; ++a)
#pragma unroll
            for (int m = 0; m < 2; ++m) acc1[a][m] = f32x4{0.f, 0.f, 0.f, 0.f};

#pragma unroll
        for (int ks = 0; ks < 2; ++ks) {
            f16x8 bf[2];
#pragma unroll
            for (int mt = 0; mt < 2; ++mt) {
                int jl = 16 * mt + c;
                f16x8 yv = yt[jl * 8 + ((4 * ks + g) ^ (c & 7))];
                f16x8 d;
#pragma unroll
                for (int i = 0; i < 8; ++i) {
                    float dd = xf[ks][i] - (float)yv[i];
                    d[i] = (f16)(dd * dd);
                }
                bf[mt] = d;
            }
#pragma unroll
            for (int ht = 0; ht < 8; ++ht) {
                f16x8 a = W1a[(ht * 2 + ks) * 64 + g * 16 + c];
                acc1[ht][0] = MFMA16(a, bf[0], acc1[ht][0]);
                acc1[ht][1] = MFMA16(a, bf[1], acc1[ht][1]);
            }
        }

        // ---- layer 2: h2^T = W2^T * relu(h1^T + tb) ----
        f32x4 acc2[8][2];
#pragma unroll
        for (int a = 0; a < 8; ++a)
#pragma unroll
            for (int m = 0; m < 2; ++m) acc2[a][m] = f32x4{0.f, 0.f, 0.f, 0.f};

#pragma unroll
        for (int ks = 0; ks < 4; ++ks) {
            f16x8 bf[2];
#pragma unroll
            for (int mt = 0; mt < 2; ++mt) {
                f16x8 d;
#pragma unroll
                for (int i = 0; i < 8; ++i) {
                    float v = acc1[2 * ks + (i >> 2)][mt][i & 3] + (float)tbo[ks][i];
                    d[i] = (f16)fmaxf(v, 0.f);
                }
                bf[mt] = d;
            }
#pragma unroll
            for (int ht = 0; ht < 8; ++ht) {
                f16x8 a = W2a[(ht * 4 + ks) * 64 + g * 16 + c];
                acc2[ht][0] = MFMA16(a, bf[0], acc2[ht][0]);
                acc2[ht][1] = MFMA16(a, bf[1], acc2[ht][1]);
            }
        }

        // ---- layer 3: K row = W3^T * relu(h2^T + b2)  (padded to 16 output rows, row 0 valid) ----
        f32x4 acc3[2];
        acc3[0] = f32x4{0.f, 0.f, 0.f, 0.f};
        acc3[1] = f32x4{0.f, 0.f, 0.f, 0.f};
#pragma unroll
        for (int ks = 0; ks < 4; ++ks) {
            f16x8 a = W3a[ks * 64 + g * 16 + c];
#pragma unroll
            for (int mt = 0; mt < 2; ++mt) {
                f16x8 d;
#pragma unroll
                for (int i = 0; i < 8; ++i) {
                    float v = acc2[2 * ks + (i >> 2)][mt][i & 3] + (float)b2o[ks][i];
                    d[i] = (f16)fmaxf(v, 0.f);
                }
                acc3[mt] = MFMA16(a, d, acc3[mt]);
            }
        }

        if (g == 0) {
            size_t base = ((size_t)(b * N + ibase + il)) * N + jbase;
            out[base + c]      = acc3[0][0] + b3v;
            out[base + 16 + c] = acc3[1][0] + b3v;
        }
    }
}

extern "C" void kernel_launch(void* const* d_in, const int* in_sizes, int n_in,
                              void* d_out, int out_size, void* d_ws, size_t ws_size,
                              hipStream_t stream) {
    const float* x  = (const float*)d_in[0];
    const float* y  = (const float*)d_in[1];
    const float* t  = (const float*)d_in[2];
    const float* W1 = (const float*)d_in[3];
    const float* b1 = (const float*)d_in[4];
    const float* W2 = (const float*)d_in[5];
    const float* b2 = (const float*)d_in[6];
    const float* W3 = (const float*)d_in[7];
    const float* b3 = (const float*)d_in[8];
    float* out = (float*)d_out;

    dim3 grid(16, 16, 4);   // (j-tiles, i-tiles, batch)
    dim3 block(256);
    pairmlp_kernel<<<grid, block, 0, stream>>>(x, y, t, W1, b1, W2, b2, W3, b3, out);
}

// Round 2
// 263.142 us; speedup vs baseline: 1.2826x; 1.2826x over previous
//
#include <hip/hip_runtime.h>

typedef _Float16 f16;
typedef _Float16 f16x8 __attribute__((ext_vector_type(8)));
typedef float f32x4 __attribute__((ext_vector_type(4)));

#define MFMA16(A, B, C) __builtin_amdgcn_mfma_f32_16x32_f16_FIXME
#undef MFMA16
#define MFMA16(A, B, C) __builtin_amdgcn_mfma_f32_16x16x32_f16((A), (B), (C), 0, 0, 0)

// B=4, N=512, X_DIM=64, T_DIM=32, H=128
// Block: 256 threads (4 waves), tile 32 i x 32 j. Grid (16,16,4).
// Per chunk (1 i-row x 32 j): layer1 -> convert acc1 to f16 B-frags (acc1 dies)
// -> layer2 -> convert -> layer3. Peak live ~115 VGPR: no spill at 128.

__global__ __launch_bounds__(256, 2)
void pairmlp_kernel(const float* __restrict__ x, const float* __restrict__ y,
                    const float* __restrict__ t, const float* __restrict__ W1,
                    const float* __restrict__ b1, const float* __restrict__ W2,
                    const float* __restrict__ b2, const float* __restrict__ W3,
                    const float* __restrict__ b3, float* __restrict__ out)
{
    const int N = 512, H = 128, XD = 64, TD = 32;

    __shared__ f16x8 W1a[1024];   // 16 KB: [ht*2+ks][g][c]: W1[32ks+8g+i][16ht+c]
    __shared__ f16x8 W2a[2048];   // 32 KB: [hpt*4+ks][g][c]: W2[32ks+16(i>=4)+4g+(i&3)][16hpt+c]
    __shared__ f16x8 W3a[256];    //  4 KB: [ks][g][c]: c==0 ? W3[h(ks,g,i)] : 0
    __shared__ f16x8 xt[256];     //  4 KB: x tile [32][64] f16, octet = row*8 + d/8
    __shared__ f16x8 yt[256];     //  4 KB: y tile, octet = row*8 + (q ^ (row&7)) (bank swizzle)
    __shared__ f16 tbsf[128];     // (t@W1[64:]+b1) in fragment order: [ks*32+g*8+i] = tb[h(ks,g,i)]
    __shared__ f16 b2sf[128];     // b2 in fragment order

    const int tid = threadIdx.x;
    const int b = blockIdx.z;
    const int ibase = blockIdx.y * 32;
    const int jbase = blockIdx.x * 32;

    // ---------------- staging ----------------
    for (int o = tid; o < 1024; o += 256) {
        int c = o & 15, g = (o >> 4) & 3, kh = o >> 6;   // kh = ht*2+ks
        int ks = kh & 1, ht = kh >> 1;
        int h = ht * 16 + c;
        f16x8 v;
#pragma unroll
        for (int i = 0; i < 8; ++i) {
            int d = 32 * ks + 8 * g + i;
            v[i] = (f16)W1[d * H + h];
        }
        W1a[o] = v;
    }
    for (int o = tid; o < 2048; o += 256) {
        int c = o & 15, g = (o >> 4) & 3, kh = o >> 6;   // kh = hpt*4+ks
        int ks = kh & 3, hpt = kh >> 2;
        int hp = hpt * 16 + c;
        f16x8 v;
#pragma unroll
        for (int i = 0; i < 8; ++i) {
            int h = 32 * ks + ((i >> 2) << 4) + 4 * g + (i & 3);
            v[i] = (f16)W2[h * H + hp];
        }
        W2a[o] = v;
    }
    {
        int o = tid;                                      // 256 octets
        int c = o & 15, g = (o >> 4) & 3, ks = o >> 6;
        f16x8 v;
#pragma unroll
        for (int i = 0; i < 8; ++i) {
            int h = 32 * ks + ((i >> 2) << 4) + 4 * g + (i & 3);
            v[i] = (c == 0) ? (f16)W3[h] : (f16)0.f;
        }
        W3a[o] = v;
    }
    if (tid < 128) {
        // fragment-ordered bias tables: tid -> (ks,g,i) -> h
        int ks = tid >> 5, g = (tid >> 3) & 3, i = tid & 7;
        int h = 32 * ks + ((i >> 2) << 4) + 4 * g + (i & 3);
        float s = b1[h];
#pragma unroll 8
        for (int d = 0; d < TD; ++d)
            s += t[b * TD + d] * W1[(XD + d) * H + h];
        tbsf[tid] = (f16)s;
        b2sf[tid] = (f16)b2[h];
    }
    {
        int o = tid;                  // 256 octets per tile
        int r = o >> 3, q = o & 7;
        const float* xp = x + ((size_t)(b * N + ibase + r)) * XD + q * 8;
        f16x8 v;
#pragma unroll
        for (int e = 0; e < 8; ++e) v[e] = (f16)xp[e];
        xt[o] = v;
        const float* yp = y + ((size_t)(b * N + jbase + r)) * XD + q * 8;
        f16x8 u;
#pragma unroll
        for (int e = 0; e < 8; ++e) u[e] = (f16)yp[e];
        yt[r * 8 + (q ^ (r & 7))] = u;
    }
    __syncthreads();

    const int w = tid >> 6;
    const int l = tid & 63;
    const int c = l & 15;
    const int g = l >> 4;
    const float b3v = b3[0];
    const f16x8* tbso = (const f16x8*)tbsf;   // octet [ks*4+g]
    const f16x8* b2so = (const f16x8*)b2sf;

    for (int ci = 0; ci < 8; ++ci) {
        const int il = w * 8 + ci;

        // x octets for this i-row: d = 32ks + 8g + e (broadcast reads)
        float xf[2][8];
        {
            f16x8 x0 = xt[il * 8 + g];
            f16x8 x1 = xt[il * 8 + 4 + g];
#pragma unroll
            for (int i = 0; i < 8; ++i) { xf[0][i] = (float)x0[i]; xf[1][i] = (float)x1[i]; }
        }

        // ---- layer 1: h1^T = W1^T * diff^T  (acc1[ht][mt][r] = h1T[16ht+4g+r][16mt+c]) ----
        f32x4 acc1[8][2];
#pragma unroll
        for (int a = 0; a < 8; ++a)
#pragma unroll
            for (int m = 0; m < 2; ++m) acc1[a][m] = f32x4{0.f, 0.f, 0.f, 0.f};

#pragma unroll
        for (int ks = 0; ks < 2; ++ks) {
            f16x8 bf[2];
#pragma unroll
            for (int mt = 0; mt < 2; ++mt) {
                int jl = 16 * mt + c;
                f16x8 yv = yt[jl * 8 + ((4 * ks + g) ^ (c & 7))];
                f16x8 d;
#pragma unroll
                for (int i = 0; i < 8; ++i) {
                    float dd = xf[ks][i] - (float)yv[i];
                    d[i] = (f16)(dd * dd);
                }
                bf[mt] = d;
            }
#pragma unroll
            for (int ht = 0; ht < 8; ++ht) {
                f16x8 a = W1a[(ht * 2 + ks) * 64 + g * 16 + c];
                acc1[ht][0] = MFMA16(a, bf[0], acc1[ht][0]);
                acc1[ht][1] = MFMA16(a, bf[1], acc1[ht][1]);
            }
        }

        // ---- convert: bf2[ks][mt] = relu(acc1 + tb) as f16 octets; acc1 dies here ----
        f16x8 bf2[4][2];
#pragma unroll
        for (int ks = 0; ks < 4; ++ks) {
            f16x8 tbv = tbso[ks * 4 + g];
#pragma unroll
            for (int mt = 0; mt < 2; ++mt) {
                f16x8 d;
#pragma unroll
                for (int i = 0; i < 8; ++i) {
                    float v = acc1[2 * ks + (i >> 2)][mt][i & 3] + (float)tbv[i];
                    d[i] = (f16)fmaxf(v, 0.f);
                }
                bf2[ks][mt] = d;
            }
        }

        // ---- layer 2: h2^T = W2^T * relu(h1^T + tb) ----
        f32x4 acc2[8][2];
#pragma unroll
        for (int a = 0; a < 8; ++a)
#pragma unroll
            for (int m = 0; m < 2; ++m) acc2[a][m] = f32x4{0.f, 0.f, 0.f, 0.f};

#pragma unroll
        for (int ks = 0; ks < 4; ++ks) {
#pragma unroll
            for (int ht = 0; ht < 8; ++ht) {
                f16x8 a = W2a[(ht * 4 + ks) * 64 + g * 16 + c];
                acc2[ht][0] = MFMA16(a, bf2[ks][0], acc2[ht][0]);
                acc2[ht][1] = MFMA16(a, bf2[ks][1], acc2[ht][1]);
            }
        }

        // ---- layer 3: K row = W3^T * relu(h2^T + b2) (row 0 of padded 16 valid) ----
        f32x4 acc3[2];
        acc3[0] = f32x4{0.f, 0.f, 0.f, 0.f};
        acc3[1] = f32x4{0.f, 0.f, 0.f, 0.f};
#pragma unroll
        for (int ks = 0; ks < 4; ++ks) {
            f16x8 a = W3a[ks * 64 + g * 16 + c];
            f16x8 b2v = b2so[ks * 4 + g];
#pragma unroll
            for (int mt = 0; mt < 2; ++mt) {
                f16x8 d;
#pragma unroll
                for (int i = 0; i < 8; ++i) {
                    float v = acc2[2 * ks + (i >> 2)][mt][i & 3] + (float)b2v[i];
                    d[i] = (f16)fmaxf(v, 0.f);
                }
                acc3[mt] = MFMA16(a, d, acc3[mt]);
            }
        }

        if (g == 0) {
            size_t base = ((size_t)(b * N + ibase + il)) * N + jbase;
            out[base + c]      = acc3[0][0] + b3v;
            out[base + 16 + c] = acc3[1][0] + b3v;
        }
    }
}

extern "C" void kernel_launch(void* const* d_in, const int* in_sizes, int n_in,
                              void* d_out, int out_size, void* d_ws, size_t ws_size,
                              hipStream_t stream) {
    const float* x  = (const float*)d_in[0];
    const float* y  = (const float*)d_in[1];
    const float* t  = (const float*)d_in[2];
    const float* W1 = (const float*)d_in[3];
    const float* b1 = (const float*)d_in[4];
    const float* W2 = (const float*)d_in[5];
    const float* b2 = (const float*)d_in[6];
    const float* W3 = (const float*)d_in[7];
    const float* b3 = (const float*)d_in[8];
    float* out = (float*)d_out;

    dim3 grid(16, 16, 4);   // (j-tiles, i-tiles, batch)
    dim3 block(256);
    pairmlp_kernel<<<grid, block, 0, stream>>>(x, y, t, W1, b1, W2, b2, W3, b3, out);
}

// Round 3
// 251.381 us; speedup vs baseline: 1.3426x; 1.0468x over previous
//
#include <hip/hip_runtime.h>

typedef _Float16 f16;
typedef _Float16 f16x8 __attribute__((ext_vector_type(8)));
typedef float f32x4 __attribute__((ext_vector_type(4)));

#define MFMA16(A, B, C) __builtin_amdgcn_mfma_f32_16x16x32_f16((A), (B), (C), 0, 0, 0)

// B=4, N=512, X_DIM=64, T_DIM=32, H=128
// Block: 256 threads (4 waves), tile 32 i x 32 j. Grid (16,16,4).
// Per chunk: 1 i-row x 16 j (mt outer loop) -> peak live ~110 VGPR, no spill at 128.
// layer1 -> convert (acc1 dies) -> layer2 -> convert -> layer3, all transposed so
// MFMA C/D feeds the next layer's B operand in-register.

__global__ __launch_bounds__(256, 2)
void pairmlp_kernel(const float* __restrict__ x, const float* __restrict__ y,
                    const float* __restrict__ t, const float* __restrict__ W1,
                    const float* __restrict__ b1, const float* __restrict__ W2,
                    const float* __restrict__ b2, const float* __restrict__ W3,
                    const float* __restrict__ b3, float* __restrict__ out)
{
    const int N = 512, H = 128, XD = 64, TD = 32;

    __shared__ f16x8 W1a[1024];   // 16 KB: [ht*2+ks][g][c]: W1[32ks+8g+i][16ht+c]
    __shared__ f16x8 W2a[2048];   // 32 KB: [hpt*4+ks][g][c]: W2[32ks+16(i>=4)+4g+(i&3)][16hpt+c]
    __shared__ f16x8 W3a[256];    //  4 KB: [ks][g][c]: c==0 ? W3[h(ks,g,i)] : 0
    __shared__ f16x8 xt[256];     //  4 KB: x tile [32][64] f16, octet = row*8 + d/8
    __shared__ f16x8 yt[256];     //  4 KB: y tile, octet = row*8 + (q ^ (row&7)) (bank swizzle)
    __shared__ f16 tbsf[128];     // (t@W1[64:]+b1) fragment order: [ks*32+g*8+i] = tb[h(ks,g,i)]
    __shared__ f16 b2sf[128];     // b2 in fragment order

    const int tid = threadIdx.x;
    const int b = blockIdx.z;
    const int ibase = blockIdx.y * 32;
    const int jbase = blockIdx.x * 32;

    // ---------------- staging ----------------
    for (int o = tid; o < 1024; o += 256) {
        int c = o & 15, g = (o >> 4) & 3, kh = o >> 6;   // kh = ht*2+ks
        int ks = kh & 1, ht = kh >> 1;
        int h = ht * 16 + c;
        f16x8 v;
#pragma unroll
        for (int i = 0; i < 8; ++i) {
            int d = 32 * ks + 8 * g + i;
            v[i] = (f16)W1[d * H + h];
        }
        W1a[o] = v;
    }
    for (int o = tid; o < 2048; o += 256) {
        int c = o & 15, g = (o >> 4) & 3, kh = o >> 6;   // kh = hpt*4+ks
        int ks = kh & 3, hpt = kh >> 2;
        int hp = hpt * 16 + c;
        f16x8 v;
#pragma unroll
        for (int i = 0; i < 8; ++i) {
            int h = 32 * ks + ((i >> 2) << 4) + 4 * g + (i & 3);
            v[i] = (f16)W2[h * H + hp];
        }
        W2a[o] = v;
    }
    {
        int o = tid;                                      // 256 octets
        int c = o & 15, g = (o >> 4) & 3, ks = o >> 6;
        f16x8 v;
#pragma unroll
        for (int i = 0; i < 8; ++i) {
            int h = 32 * ks + ((i >> 2) << 4) + 4 * g + (i & 3);
            v[i] = (c == 0) ? (f16)W3[h] : (f16)0.f;
        }
        W3a[o] = v;
    }
    if (tid < 128) {
        // fragment-ordered bias tables: tid -> (ks,g,i) -> h
        int ks = tid >> 5, g = (tid >> 3) & 3, i = tid & 7;
        int h = 32 * ks + ((i >> 2) << 4) + 4 * g + (i & 3);
        float s = b1[h];
#pragma unroll 8
        for (int d = 0; d < TD; ++d)
            s += t[b * TD + d] * W1[(XD + d) * H + h];
        tbsf[tid] = (f16)s;
        b2sf[tid] = (f16)b2[h];
    }
    {
        int o = tid;                  // 256 octets per tile
        int r = o >> 3, q = o & 7;
        const float* xp = x + ((size_t)(b * N + ibase + r)) * XD + q * 8;
        f16x8 v;
#pragma unroll
        for (int e = 0; e < 8; ++e) v[e] = (f16)xp[e];
        xt[o] = v;
        const float* yp = y + ((size_t)(b * N + jbase + r)) * XD + q * 8;
        f16x8 u;
#pragma unroll
        for (int e = 0; e < 8; ++e) u[e] = (f16)yp[e];
        yt[r * 8 + (q ^ (r & 7))] = u;
    }
    __syncthreads();

    const int w = tid >> 6;
    const int l = tid & 63;
    const int c = l & 15;
    const int g = l >> 4;
    const float b3v = b3[0];
    const f16x8* tbso = (const f16x8*)tbsf;   // octet [ks*4+g]
    const f16x8* b2so = (const f16x8*)b2sf;

    // permanent per-lane bias octets (32 VGPRs)
    f16x8 tbo[4], b2o[4];
#pragma unroll
    for (int ks = 0; ks < 4; ++ks) {
        tbo[ks] = tbso[ks * 4 + g];
        b2o[ks] = b2so[ks * 4 + g];
    }

#pragma unroll 1
    for (int mt = 0; mt < 2; ++mt) {
        const int jl = 16 * mt + c;
#pragma unroll 1
        for (int ci = 0; ci < 8; ++ci) {
            const int il = w * 8 + ci;

            // x octets for this i-row: d = 32ks + 8g + e (broadcast reads)
            float xf[2][8];
            {
                f16x8 x0 = xt[il * 8 + g];
                f16x8 x1 = xt[il * 8 + 4 + g];
#pragma unroll
                for (int i = 0; i < 8; ++i) { xf[0][i] = (float)x0[i]; xf[1][i] = (float)x1[i]; }
            }

            // ---- layer 1: acc1[ht][r] = h1T[16ht+4g+r][jl] ----
            f32x4 acc1[8];
#pragma unroll
            for (int a = 0; a < 8; ++a) acc1[a] = f32x4{0.f, 0.f, 0.f, 0.f};

#pragma unroll
            for (int ks = 0; ks < 2; ++ks) {
                f16x8 yv = yt[jl * 8 + ((4 * ks + g) ^ (c & 7))];
                f16x8 d;
#pragma unroll
                for (int i = 0; i < 8; ++i) {
                    float dd = xf[ks][i] - (float)yv[i];
                    d[i] = (f16)(dd * dd);
                }
#pragma unroll
                for (int ht = 0; ht < 8; ++ht) {
                    f16x8 a = W1a[(ht * 2 + ks) * 64 + g * 16 + c];
                    acc1[ht] = MFMA16(a, d, acc1[ht]);
                }
            }

            // ---- convert: bf2[ks] = relu(acc1 + tb) as f16 octets; acc1 dies ----
            f16x8 bf2[4];
#pragma unroll
            for (int ks = 0; ks < 4; ++ks) {
                f16x8 d;
#pragma unroll
                for (int i = 0; i < 8; ++i) {
                    float v = acc1[2 * ks + (i >> 2)][i & 3] + (float)tbo[ks][i];
                    d[i] = (f16)fmaxf(v, 0.f);
                }
                bf2[ks] = d;
            }

            // ---- layer 2 ----
            f32x4 acc2[8];
#pragma unroll
            for (int a = 0; a < 8; ++a) acc2[a] = f32x4{0.f, 0.f, 0.f, 0.f};

#pragma unroll
            for (int ks = 0; ks < 4; ++ks) {
#pragma unroll
                for (int ht = 0; ht < 8; ++ht) {
                    f16x8 a = W2a[(ht * 4 + ks) * 64 + g * 16 + c];
                    acc2[ht] = MFMA16(a, bf2[ks], acc2[ht]);
                }
            }

            // ---- layer 3 (row 0 of padded 16 valid) ----
            f32x4 acc3 = f32x4{0.f, 0.f, 0.f, 0.f};
#pragma unroll
            for (int ks = 0; ks < 4; ++ks) {
                f16x8 a = W3a[ks * 64 + g * 16 + c];
                f16x8 d;
#pragma unroll
                for (int i = 0; i < 8; ++i) {
                    float v = acc2[2 * ks + (i >> 2)][i & 3] + (float)b2o[ks][i];
                    d[i] = (f16)fmaxf(v, 0.f);
                }
                acc3 = MFMA16(a, d, acc3);
            }

            if (g == 0) {
                size_t base = ((size_t)(b * N + ibase + il)) * N + jbase;
                out[base + jl] = acc3[0] + b3v;
            }
        }
    }
}

extern "C" void kernel_launch(void* const* d_in, const int* in_sizes, int n_in,
                              void* d_out, int out_size, void* d_ws, size_t ws_size,
                              hipStream_t stream) {
    const float* x  = (const float*)d_in[0];
    const float* y  = (const float*)d_in[1];
    const float* t  = (const float*)d_in[2];
    const float* W1 = (const float*)d_in[3];
    const float* b1 = (const float*)d_in[4];
    const float* W2 = (const float*)d_in[5];
    const float* b2 = (const float*)d_in[6];
    const float* W3 = (const float*)d_in[7];
    const float* b3 = (const float*)d_in[8];
    float* out = (float*)d_out;

    dim3 grid(16, 16, 4);   // (j-tiles, i-tiles, batch)
    dim3 block(256);
    pairmlp_kernel<<<grid, block, 0, stream>>>(x, y, t, W1, b1, W2, b2, W3, b3, out);
}

// Round 4
// 88.732 us; speedup vs baseline: 3.8036x; 2.8331x over previous
//
#include <hip/hip_runtime.h>

typedef _Float16 f16;
typedef _Float16 f16x8 __attribute__((ext_vector_type(8)));
typedef float f32x4 __attribute__((ext_vector_type(4)));

#define MFMA16(A, B, C) __builtin_amdgcn_mfma_f32_16x16x32_f16((A), (B), (C), 0, 0, 0)

// B=4, N=512, X_DIM=64, T_DIM=32, H=128
// Block: 256 threads (4 waves), tile 32 i x 32 j. Grid (16,16,4).
// Per chunk: 1 i-row x 16 j (mt outer loop).
// launch_bounds(256,1): allow up to 256 arch VGPRs. LDS (60.5KB) caps residency at
// 2 blocks/CU = 8 waves/CU anyway, and 256-VGPR waves still fit 2/SIMD -> zero
// occupancy cost, eliminates the scratch spill that dominated rounds 1-3.

__global__ __launch_bounds__(256, 1)
void pairmlp_kernel(const float* __restrict__ x, const float* __restrict__ y,
                    const float* __restrict__ t, const float* __restrict__ W1,
                    const float* __restrict__ b1, const float* __restrict__ W2,
                    const float* __restrict__ b2, const float* __restrict__ W3,
                    const float* __restrict__ b3, float* __restrict__ out)
{
    const int N = 512, H = 128, XD = 64, TD = 32;

    __shared__ f16x8 W1a[1024];   // 16 KB: [ht*2+ks][g][c]: W1[32ks+8g+i][16ht+c]
    __shared__ f16x8 W2a[2048];   // 32 KB: [hpt*4+ks][g][c]: W2[32ks+16(i>=4)+4g+(i&3)][16hpt+c]
    __shared__ f16x8 W3a[256];    //  4 KB: [ks][g][c]: c==0 ? W3[h(ks,g,i)] : 0
    __shared__ f16x8 xt[256];     //  4 KB: x tile [32][64] f16, octet = row*8 + d/8
    __shared__ f16x8 yt[256];     //  4 KB: y tile, octet = row*8 + (q ^ (row&7)) (bank swizzle)
    __shared__ f16 tbsf[128];     // (t@W1[64:]+b1) fragment order: [ks*32+g*8+i] = tb[h(ks,g,i)]
    __shared__ f16 b2sf[128];     // b2 in fragment order

    const int tid = threadIdx.x;
    const int b = blockIdx.z;
    const int ibase = blockIdx.y * 32;
    const int jbase = blockIdx.x * 32;

    // ---------------- staging ----------------
    for (int o = tid; o < 1024; o += 256) {
        int c = o & 15, g = (o >> 4) & 3, kh = o >> 6;   // kh = ht*2+ks
        int ks = kh & 1, ht = kh >> 1;
        int h = ht * 16 + c;
        f16x8 v;
#pragma unroll
        for (int i = 0; i < 8; ++i) {
            int d = 32 * ks + 8 * g + i;
            v[i] = (f16)W1[d * H + h];
        }
        W1a[o] = v;
    }
    for (int o = tid; o < 2048; o += 256) {
        int c = o & 15, g = (o >> 4) & 3, kh = o >> 6;   // kh = hpt*4+ks
        int ks = kh & 3, hpt = kh >> 2;
        int hp = hpt * 16 + c;
        f16x8 v;
#pragma unroll
        for (int i = 0; i < 8; ++i) {
            int h = 32 * ks + ((i >> 2) << 4) + 4 * g + (i & 3);
            v[i] = (f16)W2[h * H + hp];
        }
        W2a[o] = v;
    }
    {
        int o = tid;                                      // 256 octets
        int c = o & 15, g = (o >> 4) & 3, ks = o >> 6;
        f16x8 v;
#pragma unroll
        for (int i = 0; i < 8; ++i) {
            int h = 32 * ks + ((i >> 2) << 4) + 4 * g + (i & 3);
            v[i] = (c == 0) ? (f16)W3[h] : (f16)0.f;
        }
        W3a[o] = v;
    }
    if (tid < 128) {
        // fragment-ordered bias tables: tid -> (ks,g,i) -> h
        int ks = tid >> 5, g = (tid >> 3) & 3, i = tid & 7;
        int h = 32 * ks + ((i >> 2) << 4) + 4 * g + (i & 3);
        float s = b1[h];
#pragma unroll 8
        for (int d = 0; d < TD; ++d)
            s += t[b * TD + d] * W1[(XD + d) * H + h];
        tbsf[tid] = (f16)s;
        b2sf[tid] = (f16)b2[h];
    }
    {
        int o = tid;                  // 256 octets per tile
        int r = o >> 3, q = o & 7;
        const float* xp = x + ((size_t)(b * N + ibase + r)) * XD + q * 8;
        f16x8 v;
#pragma unroll
        for (int e = 0; e < 8; ++e) v[e] = (f16)xp[e];
        xt[o] = v;
        const float* yp = y + ((size_t)(b * N + jbase + r)) * XD + q * 8;
        f16x8 u;
#pragma unroll
        for (int e = 0; e < 8; ++e) u[e] = (f16)yp[e];
        yt[r * 8 + (q ^ (r & 7))] = u;
    }
    __syncthreads();

    const int w = tid >> 6;
    const int l = tid & 63;
    const int c = l & 15;
    const int g = l >> 4;
    const float b3v = b3[0];
    const f16x8* tbso = (const f16x8*)tbsf;   // octet [ks*4+g]
    const f16x8* b2so = (const f16x8*)b2sf;

    // permanent per-lane bias octets (32 VGPRs)
    f16x8 tbo[4], b2o[4];
#pragma unroll
    for (int ks = 0; ks < 4; ++ks) {
        tbo[ks] = tbso[ks * 4 + g];
        b2o[ks] = b2so[ks * 4 + g];
    }

#pragma unroll 1
    for (int mt = 0; mt < 2; ++mt) {
        const int jl = 16 * mt + c;
#pragma unroll 1
        for (int ci = 0; ci < 8; ++ci) {
            const int il = w * 8 + ci;

            // x octets for this i-row: d = 32ks + 8g + e (broadcast reads)
            float xf[2][8];
            {
                f16x8 x0 = xt[il * 8 + g];
                f16x8 x1 = xt[il * 8 + 4 + g];
#pragma unroll
                for (int i = 0; i < 8; ++i) { xf[0][i] = (float)x0[i]; xf[1][i] = (float)x1[i]; }
            }

            // ---- layer 1: acc1[ht][r] = h1T[16ht+4g+r][jl] ----
            f32x4 acc1[8];
#pragma unroll
            for (int a = 0; a < 8; ++a) acc1[a] = f32x4{0.f, 0.f, 0.f, 0.f};

#pragma unroll
            for (int ks = 0; ks < 2; ++ks) {
                f16x8 yv = yt[jl * 8 + ((4 * ks + g) ^ (c & 7))];
                f16x8 d;
#pragma unroll
                for (int i = 0; i < 8; ++i) {
                    float dd = xf[ks][i] - (float)yv[i];
                    d[i] = (f16)(dd * dd);
                }
#pragma unroll
                for (int ht = 0; ht < 8; ++ht) {
                    f16x8 a = W1a[(ht * 2 + ks) * 64 + g * 16 + c];
                    acc1[ht] = MFMA16(a, d, acc1[ht]);
                }
            }

            // ---- convert: bf2[ks] = relu(acc1 + tb) as f16 octets; acc1 dies ----
            f16x8 bf2[4];
#pragma unroll
            for (int ks = 0; ks < 4; ++ks) {
                f16x8 d;
#pragma unroll
                for (int i = 0; i < 8; ++i) {
                    float v = acc1[2 * ks + (i >> 2)][i & 3] + (float)tbo[ks][i];
                    d[i] = (f16)fmaxf(v, 0.f);
                }
                bf2[ks] = d;
            }

            // ---- layer 2 ----
            f32x4 acc2[8];
#pragma unroll
            for (int a = 0; a < 8; ++a) acc2[a] = f32x4{0.f, 0.f, 0.f, 0.f};

#pragma unroll
            for (int ks = 0; ks < 4; ++ks) {
#pragma unroll
                for (int ht = 0; ht < 8; ++ht) {
                    f16x8 a = W2a[(ht * 4 + ks) * 64 + g * 16 + c];
                    acc2[ht] = MFMA16(a, bf2[ks], acc2[ht]);
                }
            }

            // ---- layer 3 (row 0 of padded 16 valid) ----
            f32x4 acc3 = f32x4{0.f, 0.f, 0.f, 0.f};
#pragma unroll
            for (int ks = 0; ks < 4; ++ks) {
                f16x8 a = W3a[ks * 64 + g * 16 + c];
                f16x8 d;
#pragma unroll
                for (int i = 0; i < 8; ++i) {
                    float v = acc2[2 * ks + (i >> 2)][i & 3] + (float)b2o[ks][i];
                    d[i] = (f16)fmaxf(v, 0.f);
                }
                acc3 = MFMA16(a, d, acc3);
            }

            if (g == 0) {
                size_t base = ((size_t)(b * N + ibase + il)) * N + jbase;
                out[base + jl] = acc3[0] + b3v;
            }
        }
    }
}

extern "C" void kernel_launch(void* const* d_in, const int* in_sizes, int n_in,
                              void* d_out, int out_size, void* d_ws, size_t ws_size,
                              hipStream_t stream) {
    const float* x  = (const float*)d_in[0];
    const float* y  = (const float*)d_in[1];
    const float* t  = (const float*)d_in[2];
    const float* W1 = (const float*)d_in[3];
    const float* b1 = (const float*)d_in[4];
    const float* W2 = (const float*)d_in[5];
    const float* b2 = (const float*)d_in[6];
    const float* W3 = (const float*)d_in[7];
    const float* b3 = (const float*)d_in[8];
    float* out = (float*)d_out;

    dim3 grid(16, 16, 4);   // (j-tiles, i-tiles, batch)
    dim3 block(256);
    pairmlp_kernel<<<grid, block, 0, stream>>>(x, y, t, W1, b1, W2, b2, W3, b3, out);
}

// Round 5
// 78.076 us; speedup vs baseline: 4.3227x; 1.1365x over previous
//
#include <hip/hip_runtime.h>

typedef _Float16 f16;
typedef _Float16 f16x8 __attribute__((ext_vector_type(8)));
typedef float f32x4 __attribute__((ext_vector_type(4)));

#define MFMA16(A, B, C) __builtin_amdgcn_mfma_f32_16x16x32_f16((A), (B), (C), 0, 0, 0)

// B=4, N=512, X_DIM=64, T_DIM=32, H=128
// Block: 256 threads (4 waves), tile 32 i x 32 j. Grid (16,16,4).
// Per chunk: 1 i-row x 32 j (mt fused) -> A-fragment LDS reads amortized over 32 outputs.
// launch_bounds(256,1): no 128-reg cap (cap caused HBM scratch spill in rounds 1-3).
// LDS 60.5KB caps residency at 2 blocks/CU = 2 waves/SIMD; <=256 VGPR keeps that.
// diff built in packed f16; layer-1/2/3 first MFMA uses shared zero C (no acc zero-init).

__global__ __launch_bounds__(256, 1)
void pairmlp_kernel(const float* __restrict__ x, const float* __restrict__ y,
                    const float* __restrict__ t, const float* __restrict__ W1,
                    const float* __restrict__ b1, const float* __restrict__ W2,
                    const float* __restrict__ b2, const float* __restrict__ W3,
                    const float* __restrict__ b3, float* __restrict__ out)
{
    const int N = 512, H = 128, XD = 64, TD = 32;

    __shared__ f16x8 W1a[1024];   // 16 KB: [ht*2+ks][g][c]: W1[32ks+8g+i][16ht+c]
    __shared__ f16x8 W2a[2048];   // 32 KB: [hpt*4+ks][g][c]: W2[32ks+16(i>=4)+4g+(i&3)][16hpt+c]
    __shared__ f16x8 W3a[256];    //  4 KB: [ks][g][c]: c==0 ? W3[h(ks,g,i)] : 0
    __shared__ f16x8 xt[256];     //  4 KB: x tile [32][64] f16, octet = row*8 + d/8
    __shared__ f16x8 yt[256];     //  4 KB: y tile, octet = row*8 + (q ^ (row&7)) (bank swizzle)
    __shared__ f16 tbsf[128];     // (t@W1[64:]+b1) fragment order: [ks*32+g*8+i] = tb[h(ks,g,i)]
    __shared__ f16 b2sf[128];     // b2 in fragment order

    const int tid = threadIdx.x;
    const int b = blockIdx.z;
    const int ibase = blockIdx.y * 32;
    const int jbase = blockIdx.x * 32;

    // ---------------- staging ----------------
    for (int o = tid; o < 1024; o += 256) {
        int c = o & 15, g = (o >> 4) & 3, kh = o >> 6;   // kh = ht*2+ks
        int ks = kh & 1, ht = kh >> 1;
        int h = ht * 16 + c;
        f16x8 v;
#pragma unroll
        for (int i = 0; i < 8; ++i) {
            int d = 32 * ks + 8 * g + i;
            v[i] = (f16)W1[d * H + h];
        }
        W1a[o] = v;
    }
    for (int o = tid; o < 2048; o += 256) {
        int c = o & 15, g = (o >> 4) & 3, kh = o >> 6;   // kh = hpt*4+ks
        int ks = kh & 3, hpt = kh >> 2;
        int hp = hpt * 16 + c;
        f16x8 v;
#pragma unroll
        for (int i = 0; i < 8; ++i) {
            int h = 32 * ks + ((i >> 2) << 4) + 4 * g + (i & 3);
            v[i] = (f16)W2[h * H + hp];
        }
        W2a[o] = v;
    }
    {
        int o = tid;                                      // 256 octets
        int c = o & 15, g = (o >> 4) & 3, ks = o >> 6;
        f16x8 v;
#pragma unroll
        for (int i = 0; i < 8; ++i) {
            int h = 32 * ks + ((i >> 2) << 4) + 4 * g + (i & 3);
            v[i] = (c == 0) ? (f16)W3[h] : (f16)0.f;
        }
        W3a[o] = v;
    }
    if (tid < 128) {
        // fragment-ordered bias tables: tid -> (ks,g,i) -> h
        int ks = tid >> 5, g = (tid >> 3) & 3, i = tid & 7;
        int h = 32 * ks + ((i >> 2) << 4) + 4 * g + (i & 3);
        float s = b1[h];
#pragma unroll 8
        for (int d = 0; d < TD; ++d)
            s += t[b * TD + d] * W1[(XD + d) * H + h];
        tbsf[tid] = (f16)s;
        b2sf[tid] = (f16)b2[h];
    }
    {
        int o = tid;                  // 256 octets per tile
        int r = o >> 3, q = o & 7;
        const float* xp = x + ((size_t)(b * N + ibase + r)) * XD + q * 8;
        f16x8 v;
#pragma unroll
        for (int e = 0; e < 8; ++e) v[e] = (f16)xp[e];
        xt[o] = v;
        const float* yp = y + ((size_t)(b * N + jbase + r)) * XD + q * 8;
        f16x8 u;
#pragma unroll
        for (int e = 0; e < 8; ++e) u[e] = (f16)yp[e];
        yt[r * 8 + (q ^ (r & 7))] = u;
    }
    __syncthreads();

    const int w = tid >> 6;
    const int l = tid & 63;
    const int c = l & 15;
    const int g = l >> 4;
    const float b3v = b3[0];
    const f16x8* tbso = (const f16x8*)tbsf;   // octet [ks*4+g]
    const f16x8* b2so = (const f16x8*)b2sf;

    // permanent per-lane bias octets (32 VGPRs)
    f16x8 tbo[4], b2o[4];
#pragma unroll
    for (int ks = 0; ks < 4; ++ks) {
        tbo[ks] = tbso[ks * 4 + g];
        b2o[ks] = b2so[ks * 4 + g];
    }

    const f32x4 zc = f32x4{0.f, 0.f, 0.f, 0.f};

#pragma unroll 1
    for (int ci = 0; ci < 8; ++ci) {
        const int il = w * 8 + ci;

        // x octets for this i-row, kept in f16 (broadcast reads)
        f16x8 xv0 = xt[il * 8 + g];        // ks=0: d = 8g + e
        f16x8 xv1 = xt[il * 8 + 4 + g];    // ks=1: d = 32 + 8g + e

        // ---- layer 1: acc1[ht][mt][r] = h1T[16ht+4g+r][16mt+c] ----
        f32x4 acc1[8][2];
#pragma unroll
        for (int ks = 0; ks < 2; ++ks) {
            f16x8 df[2];
#pragma unroll
            for (int mt = 0; mt < 2; ++mt) {
                int jl = 16 * mt + c;
                f16x8 yv = yt[jl * 8 + ((4 * ks + g) ^ (c & 7))];
                f16x8 dd = (ks ? xv1 : xv0) - yv;   // packed f16
                df[mt] = dd * dd;                    // packed f16
            }
#pragma unroll
            for (int ht = 0; ht < 8; ++ht) {
                f16x8 a = W1a[(ht * 2 + ks) * 64 + g * 16 + c];
                if (ks == 0) {
                    acc1[ht][0] = MFMA16(a, df[0], zc);
                    acc1[ht][1] = MFMA16(a, df[1], zc);
                } else {
                    acc1[ht][0] = MFMA16(a, df[0], acc1[ht][0]);
                    acc1[ht][1] = MFMA16(a, df[1], acc1[ht][1]);
                }
            }
        }

        // ---- convert: bf2[ks][mt] = relu(acc1 + tb) as f16 octets; acc1 dies ----
        f16x8 bf2[4][2];
#pragma unroll
        for (int ks = 0; ks < 4; ++ks) {
#pragma unroll
            for (int mt = 0; mt < 2; ++mt) {
                f16x8 d;
#pragma unroll
                for (int i = 0; i < 8; ++i) {
                    float v = acc1[2 * ks + (i >> 2)][mt][i & 3] + (float)tbo[ks][i];
                    d[i] = (f16)fmaxf(v, 0.f);
                }
                bf2[ks][mt] = d;
            }
        }

        // ---- layer 2 ----
        f32x4 acc2[8][2];
#pragma unroll
        for (int ks = 0; ks < 4; ++ks) {
#pragma unroll
            for (int ht = 0; ht < 8; ++ht) {
                f16x8 a = W2a[(ht * 4 + ks) * 64 + g * 16 + c];
                if (ks == 0) {
                    acc2[ht][0] = MFMA16(a, bf2[0][0], zc);
                    acc2[ht][1] = MFMA16(a, bf2[0][1], zc);
                } else {
                    acc2[ht][0] = MFMA16(a, bf2[ks][0], acc2[ht][0]);
                    acc2[ht][1] = MFMA16(a, bf2[ks][1], acc2[ht][1]);
                }
            }
        }

        // ---- layer 3 (row 0 of padded 16 valid) ----
        f32x4 acc3[2];
#pragma unroll
        for (int ks = 0; ks < 4; ++ks) {
            f16x8 a = W3a[ks * 64 + g * 16 + c];
#pragma unroll
            for (int mt = 0; mt < 2; ++mt) {
                f16x8 d;
#pragma unroll
                for (int i = 0; i < 8; ++i) {
                    float v = acc2[2 * ks + (i >> 2)][mt][i & 3] + (float)b2o[ks][i];
                    d[i] = (f16)fmaxf(v, 0.f);
                }
                if (ks == 0) acc3[mt] = MFMA16(a, d, zc);
                else         acc3[mt] = MFMA16(a, d, acc3[mt]);
            }
        }

        if (g == 0) {
            size_t base = ((size_t)(b * N + ibase + il)) * N + jbase;
            out[base + c]      = acc3[0][0] + b3v;
            out[base + 16 + c] = acc3[1][0] + b3v;
        }
    }
}

extern "C" void kernel_launch(void* const* d_in, const int* in_sizes, int n_in,
                              void* d_out, int out_size, void* d_ws, size_t ws_size,
                              hipStream_t stream) {
    const float* x  = (const float*)d_in[0];
    const float* y  = (const float*)d_in[1];
    const float* t  = (const float*)d_in[2];
    const float* W1 = (const float*)d_in[3];
    const float* b1 = (const float*)d_in[4];
    const float* W2 = (const float*)d_in[5];
    const float* b2 = (const float*)d_in[6];
    const float* W3 = (const float*)d_in[7];
    const float* b3 = (const float*)d_in[8];
    float* out = (float*)d_out;

    dim3 grid(16, 16, 4);   // (j-tiles, i-tiles, batch)
    dim3 block(256);
    pairmlp_kernel<<<grid, block, 0, stream>>>(x, y, t, W1, b1, W2, b2, W3, b3, out);
}

// Round 7
// 77.725 us; speedup vs baseline: 4.3422x; 1.0045x over previous
//
#include <hip/hip_runtime.h>

typedef _Float16 f16;
typedef _Float16 f16x2 __attribute__((ext_vector_type(2)));
typedef _Float16 f16x4 __attribute__((ext_vector_type(4)));
typedef _Float16 f16x8 __attribute__((ext_vector_type(8)));
typedef float f32x2 __attribute__((ext_vector_type(2)));
typedef float f32x4 __attribute__((ext_vector_type(4)));

#define MFMA16(A, B, C) __builtin_amdgcn_mfma_f32_16x16x32_f16((A), (B), (C), 0, 0, 0)

static __device__ __forceinline__ f16x2 cvt2(f32x2 v) {
    return __builtin_bit_cast(f16x2, __builtin_amdgcn_cvt_pkrtz(v.x, v.y));
}
static __device__ __forceinline__ f32x2 relu2(f32x2 v) {
    return __builtin_elementwise_max(v, f32x2{0.f, 0.f});
}
static __device__ __forceinline__ f16x8 pack8(f16x2 a, f16x2 b, f16x2 c, f16x2 d) {
    f16x4 lo = __builtin_shufflevector(a, b, 0, 1, 2, 3);
    f16x4 hi = __builtin_shufflevector(c, d, 0, 1, 2, 3);
    return __builtin_shufflevector(lo, hi, 0, 1, 2, 3, 4, 5, 6, 7);
}

// B=4, N=512, X_DIM=64, T_DIM=32, H=128
// Block: 256 threads (4 waves), tile 32 i x 32 j. Grid (16,16,4).
// Per chunk: 1 i-row x 32 j. Packed epilogues (pk_add_f32 + pk_max_f32 + cvt_pkrtz),
// layer 3 as v_dot2_f32_f16 + shfl-xor reduce (padded MFMA removed, W3a LDS removed).
// launch_bounds(256,1): the (256,2) 128-reg cap caused HBM scratch spill in rounds 1-3.

__global__ __launch_bounds__(256, 1)
void pairmlp_kernel(const float* __restrict__ x, const float* __restrict__ y,
                    const float* __restrict__ t, const float* __restrict__ W1,
                    const float* __restrict__ b1, const float* __restrict__ W2,
                    const float* __restrict__ b2, const float* __restrict__ W3,
                    const float* __restrict__ b3, float* __restrict__ out)
{
    const int N = 512, H = 128, XD = 64, TD = 32;

    __shared__ f16x8 W1a[1024];   // 16 KB: [ht*2+ks][g][c]: W1[32ks+8g+i][16ht+c]
    __shared__ f16x8 W2a[2048];   // 32 KB: [hpt*4+ks][g][c]: W2[32ks+16(i>=4)+4g+(i&3)][16hpt+c]
    __shared__ f16x8 xt[256];     //  4 KB: x tile [32][64] f16, octet = row*8 + d/8
    __shared__ f16x8 yt[256];     //  4 KB: y tile, octet = row*8 + (q ^ (row&7)) (bank swizzle)
    __shared__ float tbs[128];    // t @ W1[64:] + b1 (plain h order, f32)

    const int tid = threadIdx.x;
    const int b = blockIdx.z;
    const int ibase = blockIdx.y * 32;
    const int jbase = blockIdx.x * 32;

    // ---------------- staging ----------------
    for (int o = tid; o < 1024; o += 256) {
        int c = o & 15, g = (o >> 4) & 3, kh = o >> 6;   // kh = ht*2+ks
        int ks = kh & 1, ht = kh >> 1;
        int h = ht * 16 + c;
        f16x8 v;
#pragma unroll
        for (int i = 0; i < 8; ++i) {
            int d = 32 * ks + 8 * g + i;
            v[i] = (f16)W1[d * H + h];
        }
        W1a[o] = v;
    }
    for (int o = tid; o < 2048; o += 256) {
        int c = o & 15, g = (o >> 4) & 3, kh = o >> 6;   // kh = hpt*4+ks
        int ks = kh & 3, hpt = kh >> 2;
        int hp = hpt * 16 + c;
        f16x8 v;
#pragma unroll
        for (int i = 0; i < 8; ++i) {
            int h = 32 * ks + ((i >> 2) << 4) + 4 * g + (i & 3);
            v[i] = (f16)W2[h * H + hp];
        }
        W2a[o] = v;
    }
    if (tid < 128) {
        float s = b1[tid];
#pragma unroll 8
        for (int d = 0; d < TD; ++d)
            s += t[b * TD + d] * W1[(XD + d) * H + tid];
        tbs[tid] = s;
    }
    {
        int o = tid;                  // 256 octets per tile
        int r = o >> 3, q = o & 7;
        const float* xp = x + ((size_t)(b * N + ibase + r)) * XD + q * 8;
        f16x8 v;
#pragma unroll
        for (int e = 0; e < 8; ++e) v[e] = (f16)xp[e];
        xt[o] = v;
        const float* yp = y + ((size_t)(b * N + jbase + r)) * XD + q * 8;
        f16x8 u;
#pragma unroll
        for (int e = 0; e < 8; ++e) u[e] = (f16)yp[e];
        yt[r * 8 + (q ^ (r & 7))] = u;
    }
    __syncthreads();

    const int w = tid >> 6;
    const int l = tid & 63;
    const int c = l & 15;
    const int g = l >> 4;
    const float b3v = b3[0];

    // permanent per-lane bias/weight pair tables
    f32x2 tbo2[4][4];               // [ks][hi*2+p] = tb pairs at h = 32ks+16hi+4g+2p
#pragma unroll
    for (int ks = 0; ks < 4; ++ks)
#pragma unroll
        for (int q = 0; q < 4; ++q) {
            int h0 = 32 * ks + 16 * (q >> 1) + 4 * g + 2 * (q & 1);
            tbo2[ks][q] = f32x2{tbs[h0], tbs[h0 + 1]};
        }
    f32x2 b2p[8][2];                // [ht][p] = b2 pairs at h' = 16ht+4g+2p
    f16x2 w3p[8][2];                // [ht][p] = W3 pairs
#pragma unroll
    for (int ht = 0; ht < 8; ++ht)
#pragma unroll
        for (int p = 0; p < 2; ++p) {
            int h0 = 16 * ht + 4 * g + 2 * p;
            b2p[ht][p] = f32x2{b2[h0], b2[h0 + 1]};
            w3p[ht][p] = f16x2{(f16)W3[h0], (f16)W3[h0 + 1]};
        }

    const f32x4 zc = f32x4{0.f, 0.f, 0.f, 0.f};

#pragma unroll 1
    for (int ci = 0; ci < 8; ++ci) {
        const int il = w * 8 + ci;

        // x octets for this i-row (broadcast reads)
        f16x8 xv0 = xt[il * 8 + g];        // ks=0: d = 8g + e
        f16x8 xv1 = xt[il * 8 + 4 + g];    // ks=1: d = 32 + 8g + e

        // ---- layer 1: acc1[ht][mt][r] = h1T[16ht+4g+r][16mt+c] ----
        f32x4 acc1[8][2];
#pragma unroll
        for (int ks = 0; ks < 2; ++ks) {
            f16x8 df[2];
#pragma unroll
            for (int mt = 0; mt < 2; ++mt) {
                int jl = 16 * mt + c;
                f16x8 yv = yt[jl * 8 + ((4 * ks + g) ^ (c & 7))];
                f16x8 dd = (ks ? xv1 : xv0) - yv;   // v_pk_sub_f16
                df[mt] = dd * dd;                    // v_pk_mul_f16
            }
#pragma unroll
            for (int ht = 0; ht < 8; ++ht) {
                f16x8 a = W1a[(ht * 2 + ks) * 64 + g * 16 + c];
                if (ks == 0) {
                    acc1[ht][0] = MFMA16(a, df[0], zc);
                    acc1[ht][1] = MFMA16(a, df[1], zc);
                } else {
                    acc1[ht][0] = MFMA16(a, df[0], acc1[ht][0]);
                    acc1[ht][1] = MFMA16(a, df[1], acc1[ht][1]);
                }
            }
        }

        // ---- packed convert: bf2[ks][mt] = relu(acc1 + tb) as f16 octets; acc1 dies ----
        f16x8 bf2[4][2];
#pragma unroll
        for (int ks = 0; ks < 4; ++ks) {
#pragma unroll
            for (int mt = 0; mt < 2; ++mt) {
                f32x4 A = acc1[2 * ks][mt];
                f32x4 Bv = acc1[2 * ks + 1][mt];
                f32x2 r0 = relu2(f32x2{A[0], A[1]} + tbo2[ks][0]);
                f32x2 r1 = relu2(f32x2{A[2], A[3]} + tbo2[ks][1]);
                f32x2 r2 = relu2(f32x2{Bv[0], Bv[1]} + tbo2[ks][2]);
                f32x2 r3 = relu2(f32x2{Bv[2], Bv[3]} + tbo2[ks][3]);
                bf2[ks][mt] = pack8(cvt2(r0), cvt2(r1), cvt2(r2), cvt2(r3));
            }
        }

        // ---- layer 2 ----
        f32x4 acc2[8][2];
#pragma unroll
        for (int ks = 0; ks < 4; ++ks) {
#pragma unroll
            for (int ht = 0; ht < 8; ++ht) {
                f16x8 a = W2a[(ht * 4 + ks) * 64 + g * 16 + c];
                if (ks == 0) {
                    acc2[ht][0] = MFMA16(a, bf2[0][0], zc);
                    acc2[ht][1] = MFMA16(a, bf2[0][1], zc);
                } else {
                    acc2[ht][0] = MFMA16(a, bf2[ks][0], acc2[ht][0]);
                    acc2[ht][1] = MFMA16(a, bf2[ks][1], acc2[ht][1]);
                }
            }
        }

        // ---- layer 3: per-lane fdot2 over own 32 h' values, then shfl-xor over g ----
        float s0 = 0.f, s1 = 0.f;
#pragma unroll
        for (int ht = 0; ht < 8; ++ht) {
            f32x4 A0 = acc2[ht][0];
            f32x4 A1 = acc2[ht][1];
#pragma unroll
            for (int p = 0; p < 2; ++p) {
                f32x2 e0 = relu2(f32x2{A0[2 * p], A0[2 * p + 1]} + b2p[ht][p]);
                f32x2 e1 = relu2(f32x2{A1[2 * p], A1[2 * p + 1]} + b2p[ht][p]);
                s0 = __builtin_amdgcn_fdot2(cvt2(e0), w3p[ht][p], s0, false);
                s1 = __builtin_amdgcn_fdot2(cvt2(e1), w3p[ht][p], s1, false);
            }
        }
        s0 += __shfl_xor(s0, 16);
        s0 += __shfl_xor(s0, 32);
        s1 += __shfl_xor(s1, 16);
        s1 += __shfl_xor(s1, 32);

        if (g == 0) {
            size_t base = ((size_t)(b * N + ibase + il)) * N + jbase;
            out[base + c]      = s0 + b3v;
            out[base + 16 + c] = s1 + b3v;
        }
    }
}

extern "C" void kernel_launch(void* const* d_in, const int* in_sizes, int n_in,
                              void* d_out, int out_size, void* d_ws, size_t ws_size,
                              hipStream_t stream) {
    const float* x  = (const float*)d_in[0];
    const float* y  = (const float*)d_in[1];
    const float* t  = (const float*)d_in[2];
    const float* W1 = (const float*)d_in[3];
    const float* b1 = (const float*)d_in[4];
    const float* W2 = (const float*)d_in[5];
    const float* b2 = (const float*)d_in[6];
    const float* W3 = (const float*)d_in[7];
    const float* b3 = (const float*)d_in[8];
    float* out = (float*)d_out;

    dim3 grid(16, 16, 4);   // (j-tiles, i-tiles, batch)
    dim3 block(256);
    pairmlp_kernel<<<grid, block, 0, stream>>>(x, y, t, W1, b1, W2, b2, W3, b3, out);
}

// Round 8
// 63.389 us; speedup vs baseline: 5.3242x; 1.2262x over previous
//
#include <hip/hip_runtime.h>

typedef _Float16 f16;
typedef _Float16 f16x2 __attribute__((ext_vector_type(2)));
typedef _Float16 f16x4 __attribute__((ext_vector_type(4)));
typedef _Float16 f16x8 __attribute__((ext_vector_type(8)));
typedef float f32x2 __attribute__((ext_vector_type(2)));
typedef float f32x4 __attribute__((ext_vector_type(4)));

#define MFMA16(A, B, C) __builtin_amdgcn_mfma_f32_16x16x32_f16((A), (B), (C), 0, 0, 0)

static __device__ __forceinline__ f16x2 cvt2(f32x2 v) {
    return __builtin_bit_cast(f16x2, __builtin_amdgcn_cvt_pkrtz(v.x, v.y));
}
static __device__ __forceinline__ f16x4 cvt4(f32x4 v) {
    f16x2 a = cvt2(f32x2{v[0], v[1]});
    f16x2 b = cvt2(f32x2{v[2], v[3]});
    return __builtin_shufflevector(a, b, 0, 1, 2, 3);
}
static __device__ __forceinline__ f16x8 cvt8(f32x4 a, f32x4 b) {
    f16x4 lo = cvt4(a), hi = cvt4(b);
    return __builtin_shufflevector(lo, hi, 0, 1, 2, 3, 4, 5, 6, 7);
}

// B=4, N=512, X_DIM=64, T_DIM=32, H=128
// Block: 256 threads (4 waves), tile 32 i x 64 j. Grid (8,16,4) = 512 blocks = 2/CU.
// Per chunk: 1 i-row x 64 j -> A-fragment LDS reads amortized over 64 outputs
// (0.91 b128/output vs 1.7 at 32j). Layer-2/3 split in two ht-halves so acc2 is
// 64 regs; biases in f16 fragment order. launch_bounds(256,1): the (256,2) 128-reg
// cap caused HBM scratch spill (rounds 1-3); spill tripwire = FETCH_SIZE >> 3 MB.

__global__ __launch_bounds__(256, 1)
void pairmlp_kernel(const float* __restrict__ x, const float* __restrict__ y,
                    const float* __restrict__ t, const float* __restrict__ W1,
                    const float* __restrict__ b1, const float* __restrict__ W2,
                    const float* __restrict__ b2, const float* __restrict__ W3,
                    const float* __restrict__ b3, float* __restrict__ out)
{
    const int N = 512, H = 128, XD = 64, TD = 32;

    __shared__ f16x8 W1a[1024];   // 16 KB: [ht*2+ks][g][c]: W1[32ks+8g+i][16ht+c]
    __shared__ f16x8 W2a[2048];   // 32 KB: [hpt*4+ks][g][c]: W2[32ks+16(i>=4)+4g+(i&3)][16hpt+c]
    __shared__ f16x8 xt[256];     //  4 KB: x tile [32][64] f16, octet = row*8 + d/8
    __shared__ f16x8 yt[512];     //  8 KB: y tile [64][64] f16, octet = row*8 + (q ^ (row&7))
    __shared__ float tbs[128];    // t @ W1[64:] + b1 (plain h order, f32)

    const int tid = threadIdx.x;
    const int b = blockIdx.z;
    const int ibase = blockIdx.y * 32;
    const int jbase = blockIdx.x * 64;

    // ---------------- staging ----------------
    for (int o = tid; o < 1024; o += 256) {
        int c = o & 15, g = (o >> 4) & 3, kh = o >> 6;   // kh = ht*2+ks
        int ks = kh & 1, ht = kh >> 1;
        int h = ht * 16 + c;
        f16x8 v;
#pragma unroll
        for (int i = 0; i < 8; ++i) {
            int d = 32 * ks + 8 * g + i;
            v[i] = (f16)W1[d * H + h];
        }
        W1a[o] = v;
    }
    for (int o = tid; o < 2048; o += 256) {
        int c = o & 15, g = (o >> 4) & 3, kh = o >> 6;   // kh = hpt*4+ks
        int ks = kh & 3, hpt = kh >> 2;
        int hp = hpt * 16 + c;
        f16x8 v;
#pragma unroll
        for (int i = 0; i < 8; ++i) {
            int h = 32 * ks + ((i >> 2) << 4) + 4 * g + (i & 3);
            v[i] = (f16)W2[h * H + hp];
        }
        W2a[o] = v;
    }
    if (tid < 128) {
        float s = b1[tid];
#pragma unroll 8
        for (int d = 0; d < TD; ++d)
            s += t[b * TD + d] * W1[(XD + d) * H + tid];
        tbs[tid] = s;
    }
    {
        int o = tid;                  // x tile: 256 octets
        int r = o >> 3, q = o & 7;
        const float* xp = x + ((size_t)(b * N + ibase + r)) * XD + q * 8;
        f16x8 v;
#pragma unroll
        for (int e = 0; e < 8; ++e) v[e] = (f16)xp[e];
        xt[o] = v;
    }
#pragma unroll
    for (int oo = 0; oo < 2; ++oo) {  // y tile: 512 octets
        int o = tid + oo * 256;
        int r = o >> 3, q = o & 7;
        const float* yp = y + ((size_t)(b * N + jbase + r)) * XD + q * 8;
        f16x8 u;
#pragma unroll
        for (int e = 0; e < 8; ++e) u[e] = (f16)yp[e];
        yt[r * 8 + (q ^ (r & 7))] = u;
    }
    __syncthreads();

    const int w = tid >> 6;
    const int l = tid & 63;
    const int c = l & 15;
    const int g = l >> 4;
    const float b3v = b3[0];

    // permanent per-lane bias/weight tables (f16, fragment order) ~48 regs
    f16x8 tbo[4];                   // [ks][i]: tb at h = 32ks+16(i>=4)+4g+(i&3)
#pragma unroll
    for (int ks = 0; ks < 4; ++ks) {
        f16x8 v;
#pragma unroll
        for (int i = 0; i < 8; ++i) {
            int h = 32 * ks + ((i >> 2) << 4) + 4 * g + (i & 3);
            v[i] = (f16)tbs[h];
        }
        tbo[ks] = v;
    }
    f16x4 b2h[8], w3h[8];           // [ht][r]: value at h' = 16ht+4g+r
#pragma unroll
    for (int ht = 0; ht < 8; ++ht) {
        f16x4 bv, wv;
#pragma unroll
        for (int r = 0; r < 4; ++r) {
            int h0 = 16 * ht + 4 * g + r;
            bv[r] = (f16)b2[h0];
            wv[r] = (f16)W3[h0];
        }
        b2h[ht] = bv;
        w3h[ht] = wv;
    }

    const f32x4 zc = f32x4{0.f, 0.f, 0.f, 0.f};
    const f16x8 z8 = f16x8{};
    const f16x4 z4 = f16x4{};

#pragma unroll 1
    for (int ci = 0; ci < 8; ++ci) {
        const int il = w * 8 + ci;

        // x octets for this i-row (broadcast reads)
        f16x8 xv0 = xt[il * 8 + g];        // ks=0: d = 8g + e
        f16x8 xv1 = xt[il * 8 + 4 + g];    // ks=1: d = 32 + 8g + e

        // ---- layer 1: acc1[ht][mt][r] = h1T[16ht+4g+r][16mt+c] ----
        f32x4 acc1[8][4];
#pragma unroll
        for (int ks = 0; ks < 2; ++ks) {
            f16x8 df[4];
#pragma unroll
            for (int mt = 0; mt < 4; ++mt) {
                int jl = 16 * mt + c;
                f16x8 yv = yt[jl * 8 + ((4 * ks + g) ^ (c & 7))];
                f16x8 dd = (ks ? xv1 : xv0) - yv;   // v_pk_sub_f16
                df[mt] = dd * dd;                    // v_pk_mul_f16
            }
#pragma unroll
            for (int ht = 0; ht < 8; ++ht) {
                f16x8 a = W1a[(ht * 2 + ks) * 64 + g * 16 + c];
#pragma unroll
                for (int mt = 0; mt < 4; ++mt) {
                    if (ks == 0) acc1[ht][mt] = MFMA16(a, df[mt], zc);
                    else         acc1[ht][mt] = MFMA16(a, df[mt], acc1[ht][mt]);
                }
            }
        }

        // ---- convert: bf2[ks][mt] = relu(cvt(acc1) + tb_f16); acc1 dies ----
        f16x8 bf2[4][4];
#pragma unroll
        for (int ks = 0; ks < 4; ++ks)
#pragma unroll
            for (int mt = 0; mt < 4; ++mt) {
                f16x8 v = cvt8(acc1[2 * ks][mt], acc1[2 * ks + 1][mt]) + tbo[ks];
                bf2[ks][mt] = __builtin_elementwise_max(v, z8);
            }

        // ---- layers 2+3 in two ht-halves (acc2 only 64 regs live) ----
        float s0 = 0.f, s1 = 0.f, s2 = 0.f, s3 = 0.f;
#pragma unroll
        for (int half = 0; half < 2; ++half) {
            f32x4 acc2[4][4];
#pragma unroll
            for (int ks = 0; ks < 4; ++ks) {
#pragma unroll
                for (int hh = 0; hh < 4; ++hh) {
                    int ht = half * 4 + hh;
                    f16x8 a = W2a[(ht * 4 + ks) * 64 + g * 16 + c];
#pragma unroll
                    for (int mt = 0; mt < 4; ++mt) {
                        if (ks == 0) acc2[hh][mt] = MFMA16(a, bf2[0][mt], zc);
                        else         acc2[hh][mt] = MFMA16(a, bf2[ks][mt], acc2[hh][mt]);
                    }
                }
            }
            // layer 3 partials: e = relu(cvt(acc2)+b2), s += e . w3
#pragma unroll
            for (int hh = 0; hh < 4; ++hh) {
                int ht = half * 4 + hh;
                f16x2 wlo = __builtin_shufflevector(w3h[ht], w3h[ht], 0, 1);
                f16x2 whi = __builtin_shufflevector(w3h[ht], w3h[ht], 2, 3);
#pragma unroll
                for (int mt = 0; mt < 4; ++mt) {
                    f16x4 e = __builtin_elementwise_max(cvt4(acc2[hh][mt]) + b2h[ht], z4);
                    f16x2 elo = __builtin_shufflevector(e, e, 0, 1);
                    f16x2 ehi = __builtin_shufflevector(e, e, 2, 3);
                    float* sp = (mt == 0) ? &s0 : (mt == 1) ? &s1 : (mt == 2) ? &s2 : &s3;
                    *sp = __builtin_amdgcn_fdot2(elo, wlo, *sp, false);
                    *sp = __builtin_amdgcn_fdot2(ehi, whi, *sp, false);
                }
            }
        }

        // reduce across g (rows of the padded transpose) and store
        s0 += __shfl_xor(s0, 16); s0 += __shfl_xor(s0, 32);
        s1 += __shfl_xor(s1, 16); s1 += __shfl_xor(s1, 32);
        s2 += __shfl_xor(s2, 16); s2 += __shfl_xor(s2, 32);
        s3 += __shfl_xor(s3, 16); s3 += __shfl_xor(s3, 32);

        if (g == 0) {
            size_t base = ((size_t)(b * N + ibase + il)) * N + jbase;
            out[base + c]      = s0 + b3v;
            out[base + 16 + c] = s1 + b3v;
            out[base + 32 + c] = s2 + b3v;
            out[base + 48 + c] = s3 + b3v;
        }
    }
}

extern "C" void kernel_launch(void* const* d_in, const int* in_sizes, int n_in,
                              void* d_out, int out_size, void* d_ws, size_t ws_size,
                              hipStream_t stream) {
    const float* x  = (const float*)d_in[0];
    const float* y  = (const float*)d_in[1];
    const float* t  = (const float*)d_in[2];
    const float* W1 = (const float*)d_in[3];
    const float* b1 = (const float*)d_in[4];
    const float* W2 = (const float*)d_in[5];
    const float* b2 = (const float*)d_in[6];
    const float* W3 = (const float*)d_in[7];
    const float* b3 = (const float*)d_in[8];
    float* out = (float*)d_out;

    dim3 grid(8, 16, 4);   // (j-tiles of 64, i-tiles of 32, batch)
    dim3 block(256);
    pairmlp_kernel<<<grid, block, 0, stream>>>(x, y, t, W1, b1, W2, b2, W3, b3, out);
}